// Round 14
// baseline (1786.648 us; speedup 1.0000x reference)
//
#include <hip/hip_runtime.h>
#include <math.h>
#include <stdint.h>

#define NTOK 16384
#define DIMF 1024
#define NH 16
#define DHD 64
#define NQK 2048

typedef _Float16 half_t;
typedef __attribute__((ext_vector_type(8))) _Float16 half8;
typedef __attribute__((ext_vector_type(4))) _Float16 half4;
typedef __attribute__((ext_vector_type(4))) float floatx4;

__device__ __forceinline__ float wsum(float v) {
  v += __shfl_xor(v, 32, 64);
  v += __shfl_xor(v, 16, 64);
  v += __shfl_xor(v, 8, 64);
  v += __shfl_xor(v, 4, 64);
  v += __shfl_xor(v, 2, 64);
  v += __shfl_xor(v, 1, 64);
  return v;
}

// 16-lane sum via DPP (pure VALU, no LDS pipe).
template <int CTRL>
__device__ __forceinline__ float dpp_add(float v) {
  int t = __builtin_amdgcn_update_dpp(0, __float_as_int(v), CTRL, 0xF, 0xF, true);
  return v + __int_as_float(t);
}
__device__ __forceinline__ float wsum16(float v) {
  v = dpp_add<0xB1>(v);   // quad_perm(1,0,3,2)
  v = dpp_add<0x4E>(v);   // quad_perm(2,3,0,1)
  v = dpp_add<0x124>(v);  // row_ror:4
  v = dpp_add<0x128>(v);  // row_ror:8
  return v;
}

__device__ __forceinline__ float frcp(float x) { return __builtin_amdgcn_rcpf(x); }
__device__ __forceinline__ float fexp(float x) { return __expf(x); }
__device__ __forceinline__ float flog(float x) { return __logf(x); }
__device__ __forceinline__ float ftanh_pos(float x) {  // tanh, x >= 0
  float e = fexp(2.f * x);
  return 1.f - 2.f * frcp(e + 1.f);
}
__device__ __forceinline__ float fatanh01(float t) {  // atanh, t in [0,1)
  return 0.5f * flog((1.f + t) * frcp(1.f - t));
}

__device__ __forceinline__ void gload16(const void* g, void* lds) {
  __builtin_amdgcn_global_load_lds(
      (const __attribute__((address_space(1))) uint32_t*)(uintptr_t)g,
      (__attribute__((address_space(3))) uint32_t*)(uintptr_t)lds, 16, 0, 0);
}

struct EpiArgs {
  const float* sb;     // [16][64] projected mobius bias per head
  const float* y2;     // [16] sbn^2 per head
  const float* c_st;   // stereo curvature (c_v or c_ff)
  const float* c_at;   // attention curvature (V mode)
  const float* mask;   // [NTOK] (V mode)
  half_t* Qh;          // V mode: in-place Q -> v1 (stride qstride)
  half_t* Kh;          // V mode: raw K input (stride qstride)
  half_t* v2T;         // V mode: out v2 transposed [h*64+d][NTOK]
  half_t* xT;          // V mode: out x  transposed [h*64+e][NTOK]
  float* v2sum;        // V mode: [16][64] atomics
  int qstride;         // row stride of Qh/Kh
};

// =============== GEMM: C[M,N] = A[M,K](f16) * B[N,K]^T(f16) ===============
// R14: BK=32 + 2 blocks/CU. Three schedule variants (R7/R12/R13: 8/8/4
// barriers per K-tile, counted vmcnt) all measured IDENTICAL (~109us QK,
// MfmaUtil ~26%) -> the limiter is not read placement or barrier count;
// it's 1 block/CU (128KB LDS): during every drain/barrier NOTHING else is
// resident to use the idle pipes. Fix: halve LDS (BK=32, dbuf 2x32KB =
// 64KB) + __launch_bounds__(512,4) -> 2 blocks/CU co-resident; exposed
// drains of one block overlap the other block's compute (m114 mechanism).
// Schedule is the conservative proven form (R4): per K-step
// {read a[8]+b[4] || stage s+1 -> other buf -> 32 MFMA -> __syncthreads}.
// 32 steps, 32 barriers (half of R13), no counted-vmcnt subtlety.
// WAR: stage(s+1) targets buf cur^1 whose readers (step s-1) finished
// before s-1's closing barrier; stage is program-ordered after it.
// RAW: syncthreads at end of s drains vmcnt -> s+1's data landed.
// Chunk = 16 rows x 32 halfs = 1KB; lane (k-quad<<4)|row on both write
// (gload dest lane*16B) and read (lane*8 halfs) sides -> canonical,
// conflict-free (verified 0 conflicts all rounds).
// MODE 0: plain f16 out + bias. MODE 1: fused stereo + attn-pass1 (V).
// MODE 2: fused stereo -> fp32 out (FF, final output).
template <int MODE, typename OutT>
__global__ __launch_bounds__(512, 4) void gemm_f16(const half_t* __restrict__ A,
                                                   const half_t* __restrict__ B,
                                                   const float* __restrict__ bias,
                                                   OutT* __restrict__ C,
                                                   int M, int Nn, int K, EpiArgs ep) {
  __shared__ half_t sA[2][256 * 32];
  __shared__ half_t sB[2][256 * 32];
  const int tid = threadIdx.x;
  const int lane = tid & 63;
  const int w = tid >> 6;   // 0..7
  const int wm = w >> 2;    // 0..1 (M half)
  const int wn = w & 3;     // 0..3 (N quarter)

  // --- T1 XCD swizzle (bijective; grids here are multiples of 8) ---
  int gx = gridDim.x;
  int nwg = gx * gridDim.y;
  int lin = blockIdx.y * gx + blockIdx.x;
  int bx = blockIdx.x, by = blockIdx.y;
  if ((nwg & 7) == 0) {
    int cpx = nwg >> 3;
    int swz = (lin & 7) * cpx + (lin >> 3);
    bx = swz % gx;
    by = swz / gx;
  }
  const int n0 = bx * 256;
  const int m0 = by * 256;

  // per-wave staging bases: wave w stages chunks g=2w, 2w+1 of each tile
  const half_t* pA[2];
  const half_t* pB[2];
#pragma unroll
  for (int t = 0; t < 2; ++t) {
    int g = 2 * w + t;
    pA[t] = A + (size_t)(m0 + g * 16 + (lane & 15)) * K + ((lane >> 4) << 3);
    pB[t] = B + (size_t)(n0 + g * 16 + (lane & 15)) * K + ((lane >> 4) << 3);
  }

  // stage K-step T's A or B tile (16KB each) into LDS buffer buf
  auto stageA = [&](int T, half_t* buf) {
#pragma unroll
    for (int t = 0; t < 2; ++t)
      gload16(pA[t] + T * 32, buf + (2 * w + t) * 512);
  };
  auto stageB = [&](int T, half_t* buf) {
#pragma unroll
    for (int t = 0; t < 2; ++t)
      gload16(pB[t] + T * 32, buf + (2 * w + t) * 512);
  };

  floatx4 acc[8][4];
#pragma unroll
  for (int i = 0; i < 8; ++i)
#pragma unroll
    for (int j = 0; j < 4; ++j) acc[i][j] = (floatx4){0.f, 0.f, 0.f, 0.f};

  const int NTt = K >> 5;  // 32 for K=1024

  // prologue: stage step 0 into buf0
  stageA(0, &sA[0][0]);
  stageB(0, &sB[0][0]);
  __syncthreads();  // drains vmcnt: step0 ready

  for (int s = 0; s < NTt; ++s) {
    const int c = s & 1;
    half_t* sAc = c ? &sA[1][0] : &sA[0][0];
    half_t* sBc = c ? &sB[1][0] : &sB[0][0];
    half_t* sAn = c ? &sA[0][0] : &sA[1][0];
    half_t* sBn = c ? &sB[0][0] : &sB[1][0];

    half8 b[4], a[8];
#pragma unroll
    for (int j = 0; j < 4; ++j)
      b[j] = *(const half8*)&sBc[(wn * 4 + j) * 512 + lane * 8];
#pragma unroll
    for (int i = 0; i < 8; ++i)
      a[i] = *(const half8*)&sAc[(wm * 8 + i) * 512 + lane * 8];
    if (s + 1 < NTt) {
      stageA(s + 1, sAn);
      stageB(s + 1, sBn);
    }
    __builtin_amdgcn_s_setprio(1);
#pragma unroll
    for (int i = 0; i < 8; ++i)
#pragma unroll
      for (int j = 0; j < 4; ++j)
        acc[i][j] = __builtin_amdgcn_mfma_f32_16x16x32_f16(a[i], b[j], acc[i][j], 0, 0, 0);
    __builtin_amdgcn_s_setprio(0);
    __syncthreads();  // drains vmcnt (s+1 staged) + all reads of cur done
  }

  const int e = lane & 15;
  const int quad = lane >> 4;

  if constexpr (MODE == 0) {
#pragma unroll
    for (int j = 0; j < 4; ++j) {
      int col = n0 + wn * 64 + j * 16 + e;
      float bv = bias ? bias[col] : 0.f;
#pragma unroll
      for (int i = 0; i < 8; ++i) {
        int row = m0 + wm * 128 + i * 16 + quad * 4;
#pragma unroll
        for (int r = 0; r < 4; ++r)
          C[(size_t)(row + r) * Nn + col] = (OutT)(acc[i][j][r] + bv);
      }
    }
  } else {
    const int hb = n0 + wn * 64;  // head base col
    const int h = hb >> 6;
    const float kst = ep.c_st[h];
    const float sk = sqrtf(fmaxf(fabsf(kst), 1e-15f));
    const float rsk = frcp(sk);
    const float maxn = (1.f - 1e-5f) * rsk;
    const float mx2 = maxn * maxn;
    float sbj[4];
#pragma unroll
    for (int j = 0; j < 4; ++j) sbj[j] = ep.sb[hb + j * 16 + e];
    const float y2h = ep.y2[h];
    float ka = 0.f, v2acc[4] = {0.f, 0.f, 0.f, 0.f};
    if constexpr (MODE == 1) ka = ep.c_at[h];
    const int rowbase = m0 + wm * 128;

#pragma unroll
    for (int i = 0; i < 8; ++i) {
      half4 v2s[4], xs[4];  // MODE 1 staging: 4 consecutive tokens per (j)
#pragma unroll
      for (int r = 0; r < 4; ++r) {
        const int row = rowbase + i * 16 + quad * 4 + r;
        // MODE 1: independent global loads first (fly under transcendentals)
        float qraw[4], kraw[4];
        float mrow = 0.f;
        size_t qb = 0;
        if constexpr (MODE == 1) {
          qb = (size_t)row * ep.qstride + hb + e;
#pragma unroll
          for (int j = 0; j < 4; ++j) {
            qraw[j] = (float)ep.Qh[qb + j * 16];
            kraw[j] = (float)ep.Kh[qb + j * 16];
          }
          mrow = ep.mask[row];
        }
        float s = 0.f, dp = 0.f;
#pragma unroll
        for (int j = 0; j < 4; ++j) {
          float mv = acc[i][j][r];
          s += mv * mv;
          dp += mv * sbj[j];
        }
        s = wsum16(s);
        dp = wsum16(dp);
        // expmap0 + project
        float un = fmaxf(sqrtf(s), 1e-15f);
        float tn = ftanh_pos(un * sk) * rsk;
        float f = tn * frcp(un);
        float rn = fmaxf(tn, 1e-15f);
        if (rn > maxn) { f *= maxn * frcp(rn); rn = maxn; }
        // mobius_add(v, sb) + project
        float xy = dp * f;
        float x2 = rn * rn;
        float num1 = 1.f - 2.f * kst * xy - kst * y2h;
        float num2 = 1.f + kst * x2;
        float den = fmaxf(1.f - 2.f * kst * xy + kst * kst * x2 * y2h, 1e-15f);
        float rden = frcp(den);
        float c1 = num1 * f * rden;
        float c2 = num2 * rden;
        float o[4];
        float os = 0.f;
#pragma unroll
        for (int j = 0; j < 4; ++j) {
          o[j] = c1 * acc[i][j][r] + c2 * sbj[j];
          os += o[j] * o[j];
        }
        os = wsum16(os);
        float on = fmaxf(sqrtf(os), 1e-15f);
        if (on > maxn) {
          float sc = maxn * frcp(on);
#pragma unroll
          for (int j = 0; j < 4; ++j) o[j] *= sc;
        }
        if constexpr (MODE == 2) {
#pragma unroll
          for (int j = 0; j < 4; ++j)
            C[(size_t)row * Nn + hb + j * 16 + e] = (OutT)o[j];
        } else {
          // fused attn pass 1: v1 in-place; v2,x staged for half4 stores
          float vn2 = fminf(os, mx2);
          float pt = fmaxf(1.f + ka * vn2, 1e-15f);
          float rpt = frcp(pt);
          float gamma = fmaxf(2.f * rpt, 1e-15f);
          float gm1 = gamma - 1.f;
          float aden = fmaxf(fabsf(gm1), 1e-10f);
          float den2 = (gm1 >= 0.f) ? aden : -aden;
          float xsc = gamma * frcp(den2) * mrow;
#pragma unroll
          for (int j = 0; j < 4; ++j) {
            float q = qraw[j] * rpt;
            float v1 = (q > 0.f) ? (q + 1.f) : fexp(q);
            ep.Qh[qb + j * 16] = (half_t)v1;
            float kv = kraw[j] * rpt;
            float v2 = den2 * ((kv > 0.f) ? (kv + 1.f) : fexp(kv)) * mrow;
            v2acc[j] += v2;
            v2s[j][r] = (half_t)v2;
            xs[j][r] = (half_t)(xsc * o[j]);
          }
        }
      }
      if constexpr (MODE == 1) {
        // batched transposed stores: tokens quad*4..quad*4+3 contiguous
        const size_t tb0 = (size_t)(rowbase + i * 16 + quad * 4);
#pragma unroll
        for (int j = 0; j < 4; ++j) {
          size_t tb = (size_t)(hb + j * 16 + e) * NTOK + tb0;
          *(half4*)&ep.v2T[tb] = v2s[j];
          *(half4*)&ep.xT[tb] = xs[j];
        }
      }
    }
    if constexpr (MODE == 1) {
#pragma unroll
      for (int j = 0; j < 4; ++j) {
        float t = v2acc[j];
        t += __shfl_xor(t, 16, 64);
        t += __shfl_xor(t, 32, 64);
        if (quad == 0) atomicAdd(&ep.v2sum[h * DHD + j * 16 + e], t);
      }
    }
  }
}

// =============== weight convert fp32 -> f16 ===============================
struct WPack {
  const float* w[4];
  half_t* h[4];
};
__global__ __launch_bounds__(256) void convert_w_kernel(WPack pk) {
  int wi = blockIdx.y;
  const float* w = pk.w[wi];
  half_t* ph = pk.h[wi];
  int i = (blockIdx.x * 256 + threadIdx.x) * 4;
  float4 v = *(const float4*)&w[i];
  half4 hh = {(half_t)v.x, (half_t)v.y, (half_t)v.z, (half_t)v.w};
  *(half4*)&ph[i] = hh;
}

// ====== precompute projected mobius bias sb per head + combined QK bias ===
__global__ __launch_bounds__(128) void prep_sb_kernel(const float* __restrict__ bv,
                                                      const float* __restrict__ cv,
                                                      const float* __restrict__ bf,
                                                      const float* __restrict__ cf,
                                                      const float* __restrict__ bq,
                                                      const float* __restrict__ bk,
                                                      float* __restrict__ sbV,
                                                      float* __restrict__ y2V,
                                                      float* __restrict__ sbF,
                                                      float* __restrict__ y2F,
                                                      float* __restrict__ bqk) {
  int tid = threadIdx.x;
  for (int i = tid; i < 1024; i += 128) {
    bqk[i] = bq[i];
    bqk[1024 + i] = bk[i];
  }
  int wv = tid >> 6;
  int lane = tid & 63;
  const float* b = wv ? bf : bv;
  const float* c = wv ? cf : cv;
  float* sb = wv ? sbF : sbV;
  float* y2 = wv ? y2F : y2V;
  for (int h = 0; h < NH; ++h) {
    float k = c[h];
    float sk = sqrtf(fmaxf(fabsf(k), 1e-15f));
    float rsk = frcp(sk);
    float maxn = (1.f - 1e-5f) * rsk;
    float bb = b[h * DHD + lane];
    float bs = wsum(bb * bb);
    float bn = fmaxf(sqrtf(bs), 1e-15f);
    float tb = ftanh_pos(bn * sk) * rsk;
    float sv = tb * frcp(bn) * bb;
    float sbn = fmaxf(tb, 1e-15f);
    if (sbn > maxn) { sv *= maxn * frcp(sbn); sbn = maxn; }
    sb[h * DHD + lane] = sv;
    if (lane == 0) y2[h] = sbn * sbn;
  }
}

// =============== prep: Xh = f16(X); U = f16(logmap0(X, c_v)) ==============
__global__ __launch_bounds__(256) void prep_kernel(const float* __restrict__ X,
                                                   half_t* __restrict__ Xh,
                                                   half_t* __restrict__ U,
                                                   const float* __restrict__ c) {
  int lane = threadIdx.x & 63;
  int wid = blockIdx.x * 4 + (threadIdx.x >> 6);
  int nw = gridDim.x * 4;
  int sub = lane >> 4;
  for (int row = wid; row < NTOK; row += nw) {
#pragma unroll
    for (int ch = 0; ch < 4; ++ch) {
      int h = ch * 4 + sub;
      int idx = row * DIMF + ch * 256 + lane * 4;
      float4 x = *(const float4*)&X[idx];
      float s = x.x * x.x + x.y * x.y + x.z * x.z + x.w * x.w;
      s = wsum16(s);
      float k = c[h];
      float sk = sqrtf(fmaxf(fabsf(k), 1e-15f));
      float yn = fmaxf(sqrtf(s), 1e-15f);
      float t = fminf(yn * sk, 1.f - 1e-7f);
      float f = fatanh01(t) * frcp(sk) * frcp(yn);
      half4 xh4 = {(half_t)x.x, (half_t)x.y, (half_t)x.z, (half_t)x.w};
      *(half4*)&Xh[idx] = xh4;
      half4 u4 = {(half_t)(x.x * f), (half_t)(x.y * f), (half_t)(x.z * f), (half_t)(x.w * f)};
      *(half4*)&U[idx] = u4;
    }
  }
}

// ======= pass 2 (MFMA, streaming): ctxT[h][e][d] += xT[e,:]·v2T[d,:] ======
__global__ __launch_bounds__(256) void attn_pass2(const half_t* __restrict__ v2T,
                                                  const half_t* __restrict__ xT,
                                                  float* __restrict__ ctxT) {
  __shared__ float red[4096];
  int tid = threadIdx.x;
  int h = blockIdx.y;
  for (int i = tid; i < 4096; i += 256) red[i] = 0.f;
  __syncthreads();
  int lane = tid & 63;
  int w = tid >> 6;
  int m = lane & 15;
  int q = lane >> 4;
  const half_t* xb = xT + (size_t)h * 64 * NTOK;
  const half_t* vb = v2T + (size_t)h * 64 * NTOK;
  floatx4 acc[4][4];
#pragma unroll
  for (int i = 0; i < 4; ++i)
#pragma unroll
    for (int j = 0; j < 4; ++j) acc[i][j] = (floatx4){0.f, 0.f, 0.f, 0.f};

  int tok0 = blockIdx.x * 512 + w * 32 + q * 8;
#pragma unroll
  for (int c = 0; c < 4; ++c) {
    int tk = tok0 + c * 128;
    half8 af[4], bf[4];
#pragma unroll
    for (int i = 0; i < 4; ++i)
      af[i] = *(const half8*)&xb[(size_t)(i * 16 + m) * NTOK + tk];
#pragma unroll
    for (int j = 0; j < 4; ++j)
      bf[j] = *(const half8*)&vb[(size_t)(j * 16 + m) * NTOK + tk];
#pragma unroll
    for (int i = 0; i < 4; ++i)
#pragma unroll
      for (int j = 0; j < 4; ++j)
        acc[i][j] = __builtin_amdgcn_mfma_f32_16x16x32_f16(af[i], bf[j], acc[i][j], 0, 0, 0);
  }
  // reduce 4 waves through LDS atomics
#pragma unroll
  for (int i = 0; i < 4; ++i)
#pragma unroll
    for (int j = 0; j < 4; ++j)
#pragma unroll
      for (int r = 0; r < 4; ++r) {
        int e = i * 16 + q * 4 + r;
        int d = j * 16 + m;
        atomicAdd(&red[e * 64 + d], acc[i][j][r]);
      }
  __syncthreads();
  float* dst = ctxT + (size_t)h * 4096;
  for (int i = tid; i < 4096; i += 256) atomicAdd(&dst[i], red[i]);
}

// ======= pass 3 (MFMA): Xo = Dinv * (v1h @ ctx), fused Dinv + mobius epi
__global__ __launch_bounds__(256) void attn_pass3m(const half_t* __restrict__ v1h,
                                                   const float* __restrict__ ctxT,
                                                   const float* __restrict__ v2sum,
                                                   const float* __restrict__ c_at,
                                                   const float* __restrict__ c_ff,
                                                   half_t* __restrict__ Uff,
                                                   int sv1) {
  __shared__ half_t sctx[8 * 64 * 8];
  int tid = threadIdx.x;
  int h = blockIdx.y;
  int m0 = blockIdx.x * 64;
  for (int ci = tid; ci < 512; ci += 256) {
    int t = ci >> 6, l = ci & 63;
    int j = t & 3, ks = t >> 2;
    int e2 = j * 16 + (l & 15);
    int d = ks * 32 + (l >> 4) * 8;
    const float* src = &ctxT[h * 4096 + e2 * 64 + d];
    half8 hh;
#pragma unroll
    for (int q = 0; q < 8; ++q) hh[q] = (half_t)src[q];
    *(half8*)&sctx[ci * 8] = hh;
  }
  __syncthreads();

  int lane = tid & 63;
  int w = tid >> 6;
  int quad = lane >> 4;
  int e = lane & 15;

  const half_t* ap = v1h + (size_t)(m0 + w * 16 + e) * sv1 + h * DHD + quad * 8;
  half8 a0 = *(const half8*)ap;
  half8 a1 = *(const half8*)(ap + 32);

  const float* vsp = v2sum + h * DHD + quad * 8;
  float4 va = *(const float4*)&vsp[0];
  float4 vb = *(const float4*)&vsp[4];
  float4 vc = *(const float4*)&vsp[32];
  float4 vd = *(const float4*)&vsp[36];
  float dn = (float)a0[0] * va.x + (float)a0[1] * va.y + (float)a0[2] * va.z + (float)a0[3] * va.w +
             (float)a0[4] * vb.x + (float)a0[5] * vb.y + (float)a0[6] * vb.z + (float)a0[7] * vb.w +
             (float)a1[0] * vc.x + (float)a1[1] * vc.y + (float)a1[2] * vc.z + (float)a1[3] * vc.w +
             (float)a1[4] * vd.x + (float)a1[5] * vd.y + (float)a1[6] * vd.z + (float)a1[7] * vd.w;
  dn += __shfl_xor(dn, 16, 64);
  dn += __shfl_xor(dn, 32, 64);
  float di = frcp((dn == 0.f) ? 1e-5f : dn);

  floatx4 acc[4];
#pragma unroll
  for (int j = 0; j < 4; ++j) acc[j] = (floatx4){0.f, 0.f, 0.f, 0.f};
#pragma unroll
  for (int j = 0; j < 4; ++j) {
    half8 b0 = *(const half8*)&sctx[((0 * 4 + j) * 64 + lane) * 8];
    half8 b1 = *(const half8*)&sctx[((1 * 4 + j) * 64 + lane) * 8];
    acc[j] = __builtin_amdgcn_mfma_f32_16x16x32_f16(a0, b0, acc[j], 0, 0, 0);
    acc[j] = __builtin_amdgcn_mfma_f32_16x16x32_f16(a1, b1, acc[j], 0, 0, 0);
  }

  float ka = c_at[h];
  float sk_a = sqrtf(fmaxf(fabsf(ka), 1e-15f));
  float rsk_a = frcp(sk_a);
  float maxn_a = (1.f - 1e-5f) * rsk_a;
  float kf = c_ff[h];
  float sk_f = sqrtf(fmaxf(fabsf(kf), 1e-15f));
  float rsk_f = frcp(sk_f);

#pragma unroll
  for (int r = 0; r < 4; ++r) {
    float Di = __shfl(di, quad * 4 + r, 64);
    float v0 = acc[0][r], v1 = acc[1][r], v2 = acc[2][r], v3 = acc[3][r];
    float s = v0 * v0 + v1 * v1 + v2 * v2 + v3 * v3;
    s = wsum16(s);
    int row = m0 + w * 16 + quad * 4 + r;
    float f = Di;
    float xn = fmaxf(sqrtf(s) * Di, 1e-15f);
    if (xn > maxn_a) { f *= maxn_a * frcp(xn); xn = maxn_a; }
    float t = fminf(xn * sk_a, 1.f - 1e-7f);
    float ar = fatanh01(t) * rsk_a;
    float tk = ftanh_pos(0.5f * ar * sk_a) * rsk_a;
    f *= tk * frcp(xn);
    float nn = tk;
    if (nn > maxn_a) { f *= maxn_a * frcp(nn); nn = maxn_a; }
    float fn = fmaxf(nn, 1e-15f);
    float t2 = fminf(fn * sk_f, 1.f - 1e-7f);
    float ar2 = fatanh01(t2) * rsk_f;
    f *= ar2 * frcp(fn);
    size_t base = (size_t)row * DIMF + h * DHD + e;
    Uff[base + 0] = (half_t)(v0 * f);
    Uff[base + 16] = (half_t)(v1 * f);
    Uff[base + 32] = (half_t)(v2 * f);
    Uff[base + 48] = (half_t)(v3 * f);
  }
}

extern "C" void kernel_launch(void* const* d_in, const int* in_sizes, int n_in,
                              void* d_out, int out_size, void* d_ws, size_t ws_size,
                              hipStream_t stream) {
  const float* X = (const float*)d_in[0];
  const float* mask = (const float*)d_in[1];
  const float* Wq = (const float*)d_in[2];
  const float* bq = (const float*)d_in[3];
  const float* Wk = (const float*)d_in[4];
  const float* bk = (const float*)d_in[5];
  const float* Wv = (const float*)d_in[6];
  const float* bv = (const float*)d_in[7];
  const float* c_v = (const float*)d_in[8];
  const float* c_at = (const float*)d_in[9];
  const float* Wff = (const float*)d_in[10];
  const float* bff = (const float*)d_in[11];
  const float* c_ff = (const float*)d_in[12];
  float* out = (float*)d_out;

  const size_t NE = (size_t)NTOK * DIMF;
  float* v2sum = (float*)d_ws;         // 1024
  float* ctxT = v2sum + 1024;          // 65536
  float* sbV = ctxT + 65536;           // 1024
  float* sbF = sbV + 1024;             // 1024
  float* y2V = sbF + 1024;             // 16
  float* y2F = y2V + 16;               // 16
  float* bqk = y2F + 16;               // 2048
  half_t* H1 = (half_t*)(bqk + 2048);  // Xh -> Uff
  half_t* H2 = H1 + NE;                // Uv (logmap input for V)
  half_t* HQK = H2 + NE;               // [16384][2048]: Q|K -> v1|K
  half_t* V2T = HQK + 2 * NE;          // [16*64][16384] v2 transposed
  half_t* XT = V2T + NE;               // [16*64][16384] x transposed
  half_t* Wh0 = XT + NE;               // 4 x 2MB f16 weights (Wq,Wk contiguous!)

  WPack pk;
  pk.w[0] = Wq; pk.w[1] = Wk; pk.w[2] = Wv; pk.w[3] = Wff;
  for (int i = 0; i < 4; ++i) pk.h[i] = Wh0 + (size_t)i * DIMF * DIMF;

  EpiArgs epN{};
  EpiArgs epV{sbV, y2V, c_v, c_at, mask, HQK, HQK + 1024, V2T, XT, v2sum, NQK};
  EpiArgs epF{sbF, y2F, c_ff, nullptr, nullptr, nullptr, nullptr, nullptr, nullptr, nullptr, 0};

  convert_w_kernel<<<dim3(1024, 4), 256, 0, stream>>>(pk);
  prep_sb_kernel<<<1, 128, 0, stream>>>(bv, c_v, bff, c_ff, bq, bk, sbV, y2V, sbF, y2F, bqk);
  prep_kernel<<<512, 256, 0, stream>>>(X, H1, H2, c_v);
  hipMemsetAsync(v2sum, 0, (1024 + 65536) * sizeof(float), stream);
  // QK fused GEMM: [16384,2048] = Xh @ [Wq;Wk]^T + [bq;bk]
  gemm_f16<0, half_t><<<dim3(NQK / 256, NTOK / 256), 512, 0, stream>>>(
      H1, pk.h[0], bqk, HQK, NTOK, NQK, DIMF, epN);
  // V with fused stereo + attention pass 1 (v1 in place; v2/x transposed out)
  gemm_f16<1, half_t><<<dim3(DIMF / 256, NTOK / 256), 512, 0, stream>>>(
      H2, pk.h[2], nullptr, (half_t*)nullptr, NTOK, DIMF, DIMF, epV);
  // attention core
  attn_pass2<<<dim3(NTOK / 512, NH), 256, 0, stream>>>(V2T, XT, ctxT);
  attn_pass3m<<<dim3(NTOK / 64, NH), 256, 0, stream>>>(HQK, ctxT, v2sum, c_at, c_ff, H1, NQK);
  // FF with fused stereo -> final fp32 out
  gemm_f16<2, float><<<dim3(DIMF / 256, NTOK / 256), 512, 0, stream>>>(
      H1, pk.h[3], nullptr, out, NTOK, DIMF, DIMF, epF);
}

// Round 16
// 464.175 us; speedup vs baseline: 3.8491x; 3.8491x over previous
//
#include <hip/hip_runtime.h>
#include <math.h>
#include <stdint.h>

#define NTOK 16384
#define DIMF 1024
#define NH 16
#define DHD 64
#define NQK 2048

typedef _Float16 half_t;
typedef __attribute__((ext_vector_type(8))) _Float16 half8;
typedef __attribute__((ext_vector_type(4))) _Float16 half4;
typedef __attribute__((ext_vector_type(4))) float floatx4;

__device__ __forceinline__ float wsum(float v) {
  v += __shfl_xor(v, 32, 64);
  v += __shfl_xor(v, 16, 64);
  v += __shfl_xor(v, 8, 64);
  v += __shfl_xor(v, 4, 64);
  v += __shfl_xor(v, 2, 64);
  v += __shfl_xor(v, 1, 64);
  return v;
}

// 16-lane sum via DPP (pure VALU, no LDS pipe).
template <int CTRL>
__device__ __forceinline__ float dpp_add(float v) {
  int t = __builtin_amdgcn_update_dpp(0, __float_as_int(v), CTRL, 0xF, 0xF, true);
  return v + __int_as_float(t);
}
__device__ __forceinline__ float wsum16(float v) {
  v = dpp_add<0xB1>(v);   // quad_perm(1,0,3,2)
  v = dpp_add<0x4E>(v);   // quad_perm(2,3,0,1)
  v = dpp_add<0x124>(v);  // row_ror:4
  v = dpp_add<0x128>(v);  // row_ror:8
  return v;
}

__device__ __forceinline__ float frcp(float x) { return __builtin_amdgcn_rcpf(x); }
__device__ __forceinline__ float fexp(float x) { return __expf(x); }
__device__ __forceinline__ float flog(float x) { return __logf(x); }
__device__ __forceinline__ float ftanh_pos(float x) {  // tanh, x >= 0
  float e = fexp(2.f * x);
  return 1.f - 2.f * frcp(e + 1.f);
}
__device__ __forceinline__ float fatanh01(float t) {  // atanh, t in [0,1)
  return 0.5f * flog((1.f + t) * frcp(1.f - t));
}

__device__ __forceinline__ void gload16(const void* g, void* lds) {
  __builtin_amdgcn_global_load_lds(
      (const __attribute__((address_space(1))) uint32_t*)(uintptr_t)g,
      (__attribute__((address_space(3))) uint32_t*)(uintptr_t)lds, 16, 0, 0);
}

struct EpiArgs {
  const float* sb;     // [16][64] projected mobius bias per head
  const float* y2;     // [16] sbn^2 per head
  const float* c_st;   // stereo curvature (c_v or c_ff)
  const float* c_at;   // attention curvature (V mode)
  const float* mask;   // [NTOK] (V mode)
  half_t* Qh;          // V mode: in-place Q -> v1 (stride qstride)
  half_t* Kh;          // V mode: raw K input (stride qstride)
  half_t* v2T;         // V mode: out v2 transposed [h*64+d][NTOK]
  half_t* xT;          // V mode: out x  transposed [h*64+e][NTOK]
  float* v2sum;        // V mode: [16][64] atomics
  int qstride;         // row stride of Qh/Kh
};

// =============== GEMM: C[M,N] = A[M,K](f16) * B[N,K]^T(f16) ===============
// R16 = R15 with the staging-ring typo FIXED: R15's P3 staged
// stageB(1,kt+2) instead of stageB(0,kt+2) -> B_ks0(kt+2) never staged,
// every tile kt>=2 computed ks0 against stale B from kt-2 (absmax 2.7e-2).
// Ring is now exactly R12's verified form (497.6us, QK 112us, VGPR 96):
//   P0: stage A_ks1(kt+1) -> other buf   (freed at (kt-1).P3)
//   P1: stage B_ks1(kt+1) -> other buf   (freed at (kt-1).P3)
//   P2: stage A_ks0(kt+2) -> cur buf     (freed at kt.P1)
//   P3: stage B_ks0(kt+2) -> cur buf     (freed at kt.P1)
// vmcnt(4) once per K-tile at P3: entering kt with 4 in flight
// (kt+1{A0,B0}... per ring: A_ks1,B_ks1 of kt+1 issued at kt-1.P0/P1 and
// A_ks0,B_ks0 of kt+1 at kt-1.P2/P3), +4 issued by kt.P0..P3 -> vmcnt(4)
// completes the 8 oldest = all four halves of kt+1. Prologue: kt0 all 4
// halves + kt1{A0,B0} = 12 loads, vmcnt(4) completes kt0's 8. Tail:
// vmcnt(0) at kt>=NTt-2. Nothing held across barriers (R8 lesson). All
// barriers block-uniform; no inline-asm ds_reads (rule 18); no LDS
// pointer arrays (gfx950 static-init bug). GEMM plateau accepted
// (R7/R12/R13 schedules all ~109us QK; R14 2-blocks/CU spilled).
// MODE 0: plain f16 out + bias. MODE 1: fused stereo + attn-pass1 (V).
// MODE 2: fused stereo -> fp32 out (FF, final output).
template <int MODE, typename OutT>
__global__ __launch_bounds__(512, 2) void gemm_f16(const half_t* __restrict__ A,
                                                   const half_t* __restrict__ B,
                                                   const float* __restrict__ bias,
                                                   OutT* __restrict__ C,
                                                   int M, int Nn, int K, EpiArgs ep) {
  __shared__ half_t sA[2][256 * 64];
  __shared__ half_t sB[2][256 * 64];
  const int tid = threadIdx.x;
  const int lane = tid & 63;
  const int w = tid >> 6;   // 0..7
  const int wm = w >> 2;    // 0..1 (M half)
  const int wn = w & 3;     // 0..3 (N quarter)

  // --- T1 XCD swizzle (bijective; grids here are multiples of 8) ---
  int gx = gridDim.x;
  int nwg = gx * gridDim.y;
  int lin = blockIdx.y * gx + blockIdx.x;
  int bx = blockIdx.x, by = blockIdx.y;
  if ((nwg & 7) == 0) {
    int cpx = nwg >> 3;
    int swz = (lin & 7) * cpx + (lin >> 3);
    bx = swz % gx;
    by = swz / gx;
  }
  const int n0 = bx * 256;
  const int m0 = by * 256;

  // per-wave staging bases: wave w stages chunks g=2w, 2w+1 of each half
  const half_t* pA[2];
  const half_t* pB[2];
#pragma unroll
  for (int t = 0; t < 2; ++t) {
    int g = 2 * w + t;
    pA[t] = A + (size_t)(m0 + g * 16 + (lane & 15)) * K + ((lane >> 4) << 3);
    pB[t] = B + (size_t)(n0 + g * 16 + (lane & 15)) * K + ((lane >> 4) << 3);
  }

  // stage half-tile: A(ks KS) or B(ks KS) of K-tile T into LDS buffer buf
  auto stageA = [&](int KS, int T, half_t* buf) {
#pragma unroll
    for (int t = 0; t < 2; ++t)
      gload16(pA[t] + KS * 32 + T * 64, buf + (KS * 16 + 2 * w + t) * 512);
  };
  auto stageB = [&](int KS, int T, half_t* buf) {
#pragma unroll
    for (int t = 0; t < 2; ++t)
      gload16(pB[t] + KS * 32 + T * 64, buf + (KS * 16 + 2 * w + t) * 512);
  };

  floatx4 acc[8][4];
#pragma unroll
  for (int i = 0; i < 8; ++i)
#pragma unroll
    for (int j = 0; j < 4; ++j) acc[i][j] = (floatx4){0.f, 0.f, 0.f, 0.f};

  const int NTt = K >> 6;  // 16 for K=1024

  // prologue: kt0{A0,B0,A1,B1} + kt1{A0,B0} = 12 loads/wave
  stageA(0, 0, &sA[0][0]);
  stageB(0, 0, &sB[0][0]);
  stageA(1, 0, &sA[0][0]);
  stageB(1, 0, &sB[0][0]);
  stageA(0, 1, &sA[1][0]);
  stageB(0, 1, &sB[1][0]);
  asm volatile("s_waitcnt vmcnt(4)" ::: "memory");  // kt0's 8 loads done
  __builtin_amdgcn_s_barrier();

  for (int kt = 0; kt < NTt; ++kt) {
    const int c = kt & 1;
    half_t* sAc = c ? &sA[1][0] : &sA[0][0];
    half_t* sBc = c ? &sB[1][0] : &sB[0][0];
    half_t* sAn = c ? &sA[0][0] : &sA[1][0];  // other A buffer (kt+1)
    half_t* sBn = c ? &sB[0][0] : &sB[1][0];  // other B buffer (kt+1)

    // ---- P0: ks0, a-rows 0..3 (b first: MFMA chases a-read tail) --------
    {
      half8 b[4], a[4];
#pragma unroll
      for (int j = 0; j < 4; ++j)
        b[j] = *(const half8*)&sBc[(wn * 4 + j) * 512 + lane * 8];
#pragma unroll
      for (int i = 0; i < 4; ++i)
        a[i] = *(const half8*)&sAc[(wm * 8 + i) * 512 + lane * 8];
      if (kt + 1 < NTt) stageA(1, kt + 1, sAn);
      __builtin_amdgcn_s_barrier();
      __builtin_amdgcn_s_setprio(1);
#pragma unroll
      for (int i = 0; i < 4; ++i)
#pragma unroll
        for (int j = 0; j < 4; ++j)
          acc[i][j] = __builtin_amdgcn_mfma_f32_16x16x32_f16(a[i], b[j], acc[i][j], 0, 0, 0);
      __builtin_amdgcn_s_setprio(0);
      __builtin_amdgcn_s_barrier();
    }

    // ---- P1: ks0, a-rows 4..7 -------------------------------------------
    {
      half8 b[4], a[4];
#pragma unroll
      for (int j = 0; j < 4; ++j)
        b[j] = *(const half8*)&sBc[(wn * 4 + j) * 512 + lane * 8];
#pragma unroll
      for (int i = 0; i < 4; ++i)
        a[i] = *(const half8*)&sAc[(wm * 8 + 4 + i) * 512 + lane * 8];
      if (kt + 1 < NTt) stageB(1, kt + 1, sBn);
      __builtin_amdgcn_s_barrier();
      __builtin_amdgcn_s_setprio(1);
#pragma unroll
      for (int i = 0; i < 4; ++i)
#pragma unroll
        for (int j = 0; j < 4; ++j)
          acc[4 + i][j] = __builtin_amdgcn_mfma_f32_16x16x32_f16(a[i], b[j], acc[4 + i][j], 0, 0, 0);
      __builtin_amdgcn_s_setprio(0);
      __builtin_amdgcn_s_barrier();
    }

    // ---- P2: ks1, a-rows 0..3 -------------------------------------------
    {
      half8 b[4], a[4];
#pragma unroll
      for (int j = 0; j < 4; ++j)
        b[j] = *(const half8*)&sBc[(16 + wn * 4 + j) * 512 + lane * 8];
#pragma unroll
      for (int i = 0; i < 4; ++i)
        a[i] = *(const half8*)&sAc[(16 + wm * 8 + i) * 512 + lane * 8];
      if (kt + 2 < NTt) stageA(0, kt + 2, sAc);
      __builtin_amdgcn_s_barrier();
      __builtin_amdgcn_s_setprio(1);
#pragma unroll
      for (int i = 0; i < 4; ++i)
#pragma unroll
        for (int j = 0; j < 4; ++j)
          acc[i][j] = __builtin_amdgcn_mfma_f32_16x16x32_f16(a[i], b[j], acc[i][j], 0, 0, 0);
      __builtin_amdgcn_s_setprio(0);
      __builtin_amdgcn_s_barrier();
    }

    // ---- P3: ks1, a-rows 4..7 -------------------------------------------
    {
      half8 b[4], a[4];
#pragma unroll
      for (int j = 0; j < 4; ++j)
        b[j] = *(const half8*)&sBc[(16 + wn * 4 + j) * 512 + lane * 8];
#pragma unroll
      for (int i = 0; i < 4; ++i)
        a[i] = *(const half8*)&sAc[(16 + wm * 8 + 4 + i) * 512 + lane * 8];
      if (kt + 2 < NTt) stageB(0, kt + 2, sBc);  // FIXED: was stageB(1,..)
      __builtin_amdgcn_s_barrier();
      __builtin_amdgcn_s_setprio(1);
#pragma unroll
      for (int i = 0; i < 4; ++i)
#pragma unroll
        for (int j = 0; j < 4; ++j)
          acc[4 + i][j] = __builtin_amdgcn_mfma_f32_16x16x32_f16(a[i], b[j], acc[4 + i][j], 0, 0, 0);
      __builtin_amdgcn_s_setprio(0);
      // counted wait once per K-tile: completes the 8 oldest = all four
      // halves of kt+1; leaves A0,B0(kt+2) in flight. Tail: drain.
      if (kt < NTt - 2)
        asm volatile("s_waitcnt vmcnt(4)" ::: "memory");
      else
        asm volatile("s_waitcnt vmcnt(0)" ::: "memory");
      __builtin_amdgcn_s_barrier();
    }
  }

  const int e = lane & 15;
  const int quad = lane >> 4;

  if constexpr (MODE == 0) {
#pragma unroll
    for (int j = 0; j < 4; ++j) {
      int col = n0 + wn * 64 + j * 16 + e;
      float bv = bias ? bias[col] : 0.f;
#pragma unroll
      for (int i = 0; i < 8; ++i) {
        int row = m0 + wm * 128 + i * 16 + quad * 4;
#pragma unroll
        for (int r = 0; r < 4; ++r)
          C[(size_t)(row + r) * Nn + col] = (OutT)(acc[i][j][r] + bv);
      }
    }
  } else {
    const int hb = n0 + wn * 64;  // head base col
    const int h = hb >> 6;
    const float kst = ep.c_st[h];
    const float sk = sqrtf(fmaxf(fabsf(kst), 1e-15f));
    const float rsk = frcp(sk);
    const float maxn = (1.f - 1e-5f) * rsk;
    const float mx2 = maxn * maxn;
    float sbj[4];
#pragma unroll
    for (int j = 0; j < 4; ++j) sbj[j] = ep.sb[hb + j * 16 + e];
    const float y2h = ep.y2[h];
    float ka = 0.f, v2acc[4] = {0.f, 0.f, 0.f, 0.f};
    if constexpr (MODE == 1) ka = ep.c_at[h];
    const int rowbase = m0 + wm * 128;

#pragma unroll
    for (int i = 0; i < 8; ++i) {
      half4 v2s[4], xs[4];  // MODE 1 staging: 4 consecutive tokens per (j)
#pragma unroll
      for (int r = 0; r < 4; ++r) {
        const int row = rowbase + i * 16 + quad * 4 + r;
        // MODE 1: independent global loads first (fly under transcendentals)
        float qraw[4], kraw[4];
        float mrow = 0.f;
        size_t qb = 0;
        if constexpr (MODE == 1) {
          qb = (size_t)row * ep.qstride + hb + e;
#pragma unroll
          for (int j = 0; j < 4; ++j) {
            qraw[j] = (float)ep.Qh[qb + j * 16];
            kraw[j] = (float)ep.Kh[qb + j * 16];
          }
          mrow = ep.mask[row];
        }
        float s = 0.f, dp = 0.f;
#pragma unroll
        for (int j = 0; j < 4; ++j) {
          float mv = acc[i][j][r];
          s += mv * mv;
          dp += mv * sbj[j];
        }
        s = wsum16(s);
        dp = wsum16(dp);
        // expmap0 + project
        float un = fmaxf(sqrtf(s), 1e-15f);
        float tn = ftanh_pos(un * sk) * rsk;
        float f = tn * frcp(un);
        float rn = fmaxf(tn, 1e-15f);
        if (rn > maxn) { f *= maxn * frcp(rn); rn = maxn; }
        // mobius_add(v, sb) + project
        float xy = dp * f;
        float x2 = rn * rn;
        float num1 = 1.f - 2.f * kst * xy - kst * y2h;
        float num2 = 1.f + kst * x2;
        float den = fmaxf(1.f - 2.f * kst * xy + kst * kst * x2 * y2h, 1e-15f);
        float rden = frcp(den);
        float c1 = num1 * f * rden;
        float c2 = num2 * rden;
        float o[4];
        float os = 0.f;
#pragma unroll
        for (int j = 0; j < 4; ++j) {
          o[j] = c1 * acc[i][j][r] + c2 * sbj[j];
          os += o[j] * o[j];
        }
        os = wsum16(os);
        float on = fmaxf(sqrtf(os), 1e-15f);
        if (on > maxn) {
          float sc = maxn * frcp(on);
#pragma unroll
          for (int j = 0; j < 4; ++j) o[j] *= sc;
        }
        if constexpr (MODE == 2) {
#pragma unroll
          for (int j = 0; j < 4; ++j)
            C[(size_t)row * Nn + hb + j * 16 + e] = (OutT)o[j];
        } else {
          // fused attn pass 1: v1 in-place; v2,x staged for half4 stores
          float vn2 = fminf(os, mx2);
          float pt = fmaxf(1.f + ka * vn2, 1e-15f);
          float rpt = frcp(pt);
          float gamma = fmaxf(2.f * rpt, 1e-15f);
          float gm1 = gamma - 1.f;
          float aden = fmaxf(fabsf(gm1), 1e-10f);
          float den2 = (gm1 >= 0.f) ? aden : -aden;
          float xsc = gamma * frcp(den2) * mrow;
#pragma unroll
          for (int j = 0; j < 4; ++j) {
            float q = qraw[j] * rpt;
            float v1 = (q > 0.f) ? (q + 1.f) : fexp(q);
            ep.Qh[qb + j * 16] = (half_t)v1;
            float kv = kraw[j] * rpt;
            float v2 = den2 * ((kv > 0.f) ? (kv + 1.f) : fexp(kv)) * mrow;
            v2acc[j] += v2;
            v2s[j][r] = (half_t)v2;
            xs[j][r] = (half_t)(xsc * o[j]);
          }
        }
      }
      if constexpr (MODE == 1) {
        // batched transposed stores: tokens quad*4..quad*4+3 contiguous
        const size_t tb0 = (size_t)(rowbase + i * 16 + quad * 4);
#pragma unroll
        for (int j = 0; j < 4; ++j) {
          size_t tb = (size_t)(hb + j * 16 + e) * NTOK + tb0;
          *(half4*)&ep.v2T[tb] = v2s[j];
          *(half4*)&ep.xT[tb] = xs[j];
        }
      }
    }
    if constexpr (MODE == 1) {
#pragma unroll
      for (int j = 0; j < 4; ++j) {
        float t = v2acc[j];
        t += __shfl_xor(t, 16, 64);
        t += __shfl_xor(t, 32, 64);
        if (quad == 0) atomicAdd(&ep.v2sum[h * DHD + j * 16 + e], t);
      }
    }
  }
}

// =============== weight convert fp32 -> f16 ===============================
struct WPack {
  const float* w[4];
  half_t* h[4];
};
__global__ __launch_bounds__(256) void convert_w_kernel(WPack pk) {
  int wi = blockIdx.y;
  const float* w = pk.w[wi];
  half_t* ph = pk.h[wi];
  int i = (blockIdx.x * 256 + threadIdx.x) * 4;
  float4 v = *(const float4*)&w[i];
  half4 hh = {(half_t)v.x, (half_t)v.y, (half_t)v.z, (half_t)v.w};
  *(half4*)&ph[i] = hh;
}

// ====== precompute projected mobius bias sb per head + combined QK bias ===
__global__ __launch_bounds__(128) void prep_sb_kernel(const float* __restrict__ bv,
                                                      const float* __restrict__ cv,
                                                      const float* __restrict__ bf,
                                                      const float* __restrict__ cf,
                                                      const float* __restrict__ bq,
                                                      const float* __restrict__ bk,
                                                      float* __restrict__ sbV,
                                                      float* __restrict__ y2V,
                                                      float* __restrict__ sbF,
                                                      float* __restrict__ y2F,
                                                      float* __restrict__ bqk) {
  int tid = threadIdx.x;
  for (int i = tid; i < 1024; i += 128) {
    bqk[i] = bq[i];
    bqk[1024 + i] = bk[i];
  }
  int wv = tid >> 6;
  int lane = tid & 63;
  const float* b = wv ? bf : bv;
  const float* c = wv ? cf : cv;
  float* sb = wv ? sbF : sbV;
  float* y2 = wv ? y2F : y2V;
  for (int h = 0; h < NH; ++h) {
    float k = c[h];
    float sk = sqrtf(fmaxf(fabsf(k), 1e-15f));
    float rsk = frcp(sk);
    float maxn = (1.f - 1e-5f) * rsk;
    float bb = b[h * DHD + lane];
    float bs = wsum(bb * bb);
    float bn = fmaxf(sqrtf(bs), 1e-15f);
    float tb = ftanh_pos(bn * sk) * rsk;
    float sv = tb * frcp(bn) * bb;
    float sbn = fmaxf(tb, 1e-15f);
    if (sbn > maxn) { sv *= maxn * frcp(sbn); sbn = maxn; }
    sb[h * DHD + lane] = sv;
    if (lane == 0) y2[h] = sbn * sbn;
  }
}

// =============== prep: Xh = f16(X); U = f16(logmap0(X, c_v)) ==============
__global__ __launch_bounds__(256) void prep_kernel(const float* __restrict__ X,
                                                   half_t* __restrict__ Xh,
                                                   half_t* __restrict__ U,
                                                   const float* __restrict__ c) {
  int lane = threadIdx.x & 63;
  int wid = blockIdx.x * 4 + (threadIdx.x >> 6);
  int nw = gridDim.x * 4;
  int sub = lane >> 4;
  for (int row = wid; row < NTOK; row += nw) {
#pragma unroll
    for (int ch = 0; ch < 4; ++ch) {
      int h = ch * 4 + sub;
      int idx = row * DIMF + ch * 256 + lane * 4;
      float4 x = *(const float4*)&X[idx];
      float s = x.x * x.x + x.y * x.y + x.z * x.z + x.w * x.w;
      s = wsum16(s);
      float k = c[h];
      float sk = sqrtf(fmaxf(fabsf(k), 1e-15f));
      float yn = fmaxf(sqrtf(s), 1e-15f);
      float t = fminf(yn * sk, 1.f - 1e-7f);
      float f = fatanh01(t) * frcp(sk) * frcp(yn);
      half4 xh4 = {(half_t)x.x, (half_t)x.y, (half_t)x.z, (half_t)x.w};
      *(half4*)&Xh[idx] = xh4;
      half4 u4 = {(half_t)(x.x * f), (half_t)(x.y * f), (half_t)(x.z * f), (half_t)(x.w * f)};
      *(half4*)&U[idx] = u4;
    }
  }
}

// ======= pass 2 (MFMA, streaming): ctxT[h][e][d] += xT[e,:]·v2T[d,:] ======
// R16: per-wave plain LDS writes + tree-sum replaces 16384 serialized
// LDS atomicAdds/block. Each wave covers all 4096 cells exactly once
// (e=(i,q,r) and d=(j,m) both bijective onto 0..63) -> no zero-init,
// one barrier. Grid unchanged (512 blocks = 2/CU at 64KB LDS).
__global__ __launch_bounds__(256) void attn_pass2(const half_t* __restrict__ v2T,
                                                  const half_t* __restrict__ xT,
                                                  float* __restrict__ ctxT) {
  __shared__ float red[4][4096];
  int tid = threadIdx.x;
  int h = blockIdx.y;
  int lane = tid & 63;
  int w = tid >> 6;
  int m = lane & 15;
  int q = lane >> 4;
  const half_t* xb = xT + (size_t)h * 64 * NTOK;
  const half_t* vb = v2T + (size_t)h * 64 * NTOK;
  floatx4 acc[4][4];
#pragma unroll
  for (int i = 0; i < 4; ++i)
#pragma unroll
    for (int j = 0; j < 4; ++j) acc[i][j] = (floatx4){0.f, 0.f, 0.f, 0.f};

  int tok0 = blockIdx.x * 512 + w * 32 + q * 8;
#pragma unroll
  for (int c = 0; c < 4; ++c) {
    int tk = tok0 + c * 128;
    half8 af[4], bf[4];
#pragma unroll
    for (int i = 0; i < 4; ++i)
      af[i] = *(const half8*)&xb[(size_t)(i * 16 + m) * NTOK + tk];
#pragma unroll
    for (int j = 0; j < 4; ++j)
      bf[j] = *(const half8*)&vb[(size_t)(j * 16 + m) * NTOK + tk];
#pragma unroll
    for (int i = 0; i < 4; ++i)
#pragma unroll
      for (int j = 0; j < 4; ++j)
        acc[i][j] = __builtin_amdgcn_mfma_f32_16x16x32_f16(af[i], bf[j], acc[i][j], 0, 0, 0);
  }
  // per-wave plain stores: wave w owns red[w]; full 4096 coverage
#pragma unroll
  for (int i = 0; i < 4; ++i)
#pragma unroll
    for (int j = 0; j < 4; ++j)
#pragma unroll
      for (int r = 0; r < 4; ++r)
        red[w][(i * 16 + q * 4 + r) * 64 + j * 16 + m] = acc[i][j][r];
  __syncthreads();
  float* dst = ctxT + (size_t)h * 4096;
  for (int idx = tid; idx < 4096; idx += 256) {
    float s2 = (red[0][idx] + red[1][idx]) + (red[2][idx] + red[3][idx]);
    atomicAdd(&dst[idx], s2);
  }
}

// ======= pass 3 (MFMA): Xo = Dinv * (v1h @ ctx), fused Dinv + mobius epi
__global__ __launch_bounds__(256) void attn_pass3m(const half_t* __restrict__ v1h,
                                                   const float* __restrict__ ctxT,
                                                   const float* __restrict__ v2sum,
                                                   const float* __restrict__ c_at,
                                                   const float* __restrict__ c_ff,
                                                   half_t* __restrict__ Uff,
                                                   int sv1) {
  __shared__ half_t sctx[8 * 64 * 8];
  int tid = threadIdx.x;
  int h = blockIdx.y;
  int m0 = blockIdx.x * 64;
  for (int ci = tid; ci < 512; ci += 256) {
    int t = ci >> 6, l = ci & 63;
    int j = t & 3, ks = t >> 2;
    int e2 = j * 16 + (l & 15);
    int d = ks * 32 + (l >> 4) * 8;
    const float* src = &ctxT[h * 4096 + e2 * 64 + d];
    half8 hh;
#pragma unroll
    for (int q = 0; q < 8; ++q) hh[q] = (half_t)src[q];
    *(half8*)&sctx[ci * 8] = hh;
  }
  __syncthreads();

  int lane = tid & 63;
  int w = tid >> 6;
  int quad = lane >> 4;
  int e = lane & 15;

  const half_t* ap = v1h + (size_t)(m0 + w * 16 + e) * sv1 + h * DHD + quad * 8;
  half8 a0 = *(const half8*)ap;
  half8 a1 = *(const half8*)(ap + 32);

  const float* vsp = v2sum + h * DHD + quad * 8;
  float4 va = *(const float4*)&vsp[0];
  float4 vb = *(const float4*)&vsp[4];
  float4 vc = *(const float4*)&vsp[32];
  float4 vd = *(const float4*)&vsp[36];
  float dn = (float)a0[0] * va.x + (float)a0[1] * va.y + (float)a0[2] * va.z + (float)a0[3] * va.w +
             (float)a0[4] * vb.x + (float)a0[5] * vb.y + (float)a0[6] * vb.z + (float)a0[7] * vb.w +
             (float)a1[0] * vc.x + (float)a1[1] * vc.y + (float)a1[2] * vc.z + (float)a1[3] * vc.w +
             (float)a1[4] * vd.x + (float)a1[5] * vd.y + (float)a1[6] * vd.z + (float)a1[7] * vd.w;
  dn += __shfl_xor(dn, 16, 64);
  dn += __shfl_xor(dn, 32, 64);
  float di = frcp((dn == 0.f) ? 1e-5f : dn);

  floatx4 acc[4];
#pragma unroll
  for (int j = 0; j < 4; ++j) acc[j] = (floatx4){0.f, 0.f, 0.f, 0.f};
#pragma unroll
  for (int j = 0; j < 4; ++j) {
    half8 b0 = *(const half8*)&sctx[((0 * 4 + j) * 64 + lane) * 8];
    half8 b1 = *(const half8*)&sctx[((1 * 4 + j) * 64 + lane) * 8];
    acc[j] = __builtin_amdgcn_mfma_f32_16x16x32_f16(a0, b0, acc[j], 0, 0, 0);
    acc[j] = __builtin_amdgcn_mfma_f32_16x16x32_f16(a1, b1, acc[j], 0, 0, 0);
  }

  float ka = c_at[h];
  float sk_a = sqrtf(fmaxf(fabsf(ka), 1e-15f));
  float rsk_a = frcp(sk_a);
  float maxn_a = (1.f - 1e-5f) * rsk_a;
  float kf = c_ff[h];
  float sk_f = sqrtf(fmaxf(fabsf(kf), 1e-15f));
  float rsk_f = frcp(sk_f);

#pragma unroll
  for (int r = 0; r < 4; ++r) {
    float Di = __shfl(di, quad * 4 + r, 64);
    float v0 = acc[0][r], v1 = acc[1][r], v2 = acc[2][r], v3 = acc[3][r];
    float s = v0 * v0 + v1 * v1 + v2 * v2 + v3 * v3;
    s = wsum16(s);
    int row = m0 + w * 16 + quad * 4 + r;
    float f = Di;
    float xn = fmaxf(sqrtf(s) * Di, 1e-15f);
    if (xn > maxn_a) { f *= maxn_a * frcp(xn); xn = maxn_a; }
    float t = fminf(xn * sk_a, 1.f - 1e-7f);
    float ar = fatanh01(t) * rsk_a;
    float tk = ftanh_pos(0.5f * ar * sk_a) * rsk_a;
    f *= tk * frcp(xn);
    float nn = tk;
    if (nn > maxn_a) { f *= maxn_a * frcp(nn); nn = maxn_a; }
    float fn = fmaxf(nn, 1e-15f);
    float t2 = fminf(fn * sk_f, 1.f - 1e-7f);
    float ar2 = fatanh01(t2) * rsk_f;
    f *= ar2 * frcp(fn);
    size_t base = (size_t)row * DIMF + h * DHD + e;
    Uff[base + 0] = (half_t)(v0 * f);
    Uff[base + 16] = (half_t)(v1 * f);
    Uff[base + 32] = (half_t)(v2 * f);
    Uff[base + 48] = (half_t)(v3 * f);
  }
}

extern "C" void kernel_launch(void* const* d_in, const int* in_sizes, int n_in,
                              void* d_out, int out_size, void* d_ws, size_t ws_size,
                              hipStream_t stream) {
  const float* X = (const float*)d_in[0];
  const float* mask = (const float*)d_in[1];
  const float* Wq = (const float*)d_in[2];
  const float* bq = (const float*)d_in[3];
  const float* Wk = (const float*)d_in[4];
  const float* bk = (const float*)d_in[5];
  const float* Wv = (const float*)d_in[6];
  const float* bv = (const float*)d_in[7];
  const float* c_v = (const float*)d_in[8];
  const float* c_at = (const float*)d_in[9];
  const float* Wff = (const float*)d_in[10];
  const float* bff = (const float*)d_in[11];
  const float* c_ff = (const float*)d_in[12];
  float* out = (float*)d_out;

  const size_t NE = (size_t)NTOK * DIMF;
  float* v2sum = (float*)d_ws;         // 1024
  float* ctxT = v2sum + 1024;          // 65536
  float* sbV = ctxT + 65536;           // 1024
  float* sbF = sbV + 1024;             // 1024
  float* y2V = sbF + 1024;             // 16
  float* y2F = y2V + 16;               // 16
  float* bqk = y2F + 16;               // 2048
  half_t* H1 = (half_t*)(bqk + 2048);  // Xh -> Uff
  half_t* H2 = H1 + NE;                // Uv (logmap input for V)
  half_t* HQK = H2 + NE;               // [16384][2048]: Q|K -> v1|K
  half_t* V2T = HQK + 2 * NE;          // [16*64][16384] v2 transposed
  half_t* XT = V2T + NE;               // [16*64][16384] x transposed
  half_t* Wh0 = XT + NE;               // 4 x 2MB f16 weights (Wq,Wk contiguous!)

  WPack pk;
  pk.w[0] = Wq; pk.w[1] = Wk; pk.w[2] = Wv; pk.w[3] = Wff;
  for (int i = 0; i < 4; ++i) pk.h[i] = Wh0 + (size_t)i * DIMF * DIMF;

  EpiArgs epN{};
  EpiArgs epV{sbV, y2V, c_v, c_at, mask, HQK, HQK + 1024, V2T, XT, v2sum, NQK};
  EpiArgs epF{sbF, y2F, c_ff, nullptr, nullptr, nullptr, nullptr, nullptr, nullptr, nullptr, 0};

  convert_w_kernel<<<dim3(1024, 4), 256, 0, stream>>>(pk);
  prep_sb_kernel<<<1, 128, 0, stream>>>(bv, c_v, bff, c_ff, bq, bk, sbV, y2V, sbF, y2F, bqk);
  prep_kernel<<<512, 256, 0, stream>>>(X, H1, H2, c_v);
  hipMemsetAsync(v2sum, 0, (1024 + 65536) * sizeof(float), stream);
  // QK fused GEMM: [16384,2048] = Xh @ [Wq;Wk]^T + [bq;bk]
  gemm_f16<0, half_t><<<dim3(NQK / 256, NTOK / 256), 512, 0, stream>>>(
      H1, pk.h[0], bqk, HQK, NTOK, NQK, DIMF, epN);
  // V with fused stereo + attention pass 1 (v1 in place; v2/x transposed out)
  gemm_f16<1, half_t><<<dim3(DIMF / 256, NTOK / 256), 512, 0, stream>>>(
      H2, pk.h[2], nullptr, (half_t*)nullptr, NTOK, DIMF, DIMF, epV);
  // attention core
  attn_pass2<<<dim3(NTOK / 512, NH), 256, 0, stream>>>(V2T, XT, ctxT);
  attn_pass3m<<<dim3(NTOK / 64, NH), 256, 0, stream>>>(HQK, ctxT, v2sum, c_at, c_ff, H1, NQK);
  // FF with fused stereo -> final fp32 out
  gemm_f16<2, float><<<dim3(DIMF / 256, NTOK / 256), 512, 0, stream>>>(
      H1, pk.h[3], nullptr, out, NTOK, DIMF, DIMF, epF);
}